// Round 2
// baseline (10695.733 us; speedup 1.0000x reference)
//
#include <hip/hip_runtime.h>
#include <hip/hip_bf16.h>

// Sizes
#define BB 16
#define NSEQ 20
#define HEADS 8
#define DH 96
#define DIM 768
#define FF 3072
#define KMEM 32768
#define NCHUNK 4
#define CHUNK 8192
#define KCHUNK 512

// ---------------------------------------------------------------- GEMM
// C[m][n] = act(scale * sum_k A[m][k]*B[k][n] + bias[n]) + resid[m][n]
// Block: 256 threads = 64 n-lanes x 4 k-slices. Tile: 16 rows x 64 cols.
__global__ __launch_bounds__(256) void gemm_k(const float* __restrict__ A, const float* __restrict__ B,
    const float* __restrict__ bias, const float* __restrict__ resid, float* __restrict__ C,
    int M, int N, int K, int lda, int ldc, float scale, int act)
{
    __shared__ float a_sh[16 * KCHUNK];
    __shared__ float red[4 * 16 * 64];
    int tid = threadIdx.x;
    int n0 = blockIdx.x * 64;
    int m0 = blockIdx.y * 16;
    int lane_n = tid & 63;
    int slice = tid >> 6;
    int n = n0 + lane_n;
    float acc[16];
#pragma unroll
    for (int mi = 0; mi < 16; mi++) acc[mi] = 0.f;
    for (int kc = 0; kc < K; kc += KCHUNK) {
        int kl = min(KCHUNK, K - kc);
        for (int idx = tid; idx < 16 * kl; idx += 256) {
            int mi = idx / kl, kk = idx - mi * kl;
            a_sh[mi * KCHUNK + kk] = A[(size_t)(m0 + mi) * lda + kc + kk];
        }
        __syncthreads();
        if (n < N) {
            for (int k = slice; k < kl; k += 4) {
                float bv = B[(size_t)(kc + k) * N + n];
#pragma unroll
                for (int mi = 0; mi < 16; mi++) acc[mi] = fmaf(a_sh[mi * KCHUNK + k], bv, acc[mi]);
            }
        }
        __syncthreads();
    }
#pragma unroll
    for (int mi = 0; mi < 16; mi++) red[(slice * 16 + mi) * 64 + lane_n] = acc[mi];
    __syncthreads();
#pragma unroll
    for (int p = 0; p < 4; p++) {
        int idx = tid + p * 256;
        int mi = idx >> 6, nl = idx & 63;
        int nn = n0 + nl;
        if (nn < N) {
            float v = red[(0 * 16 + mi) * 64 + nl] + red[(1 * 16 + mi) * 64 + nl]
                    + red[(2 * 16 + mi) * 64 + nl] + red[(3 * 16 + mi) * 64 + nl];
            v *= scale;
            if (bias) v += bias[nn];
            if (act) {
                float xx = v;
                float tt = 0.7978845608028654f * (xx + 0.044715f * xx * xx * xx);
                v = 0.5f * xx * (1.0f + tanhf(tt));
            }
            if (resid) v += resid[(size_t)(m0 + mi) * ldc + nn];
            C[(size_t)(m0 + mi) * ldc + nn] = v;
        }
    }
}

// ---------------------------------------------------------------- LayerNorm
__global__ __launch_bounds__(256) void ln_k(const float* __restrict__ x, const float* __restrict__ g,
    const float* __restrict__ bb, float* __restrict__ y)
{
    int row = blockIdx.x;
    const float* xr = x + (size_t)row * DIM;
    int tid = threadIdx.x;
    float v0 = xr[tid], v1 = xr[tid + 256], v2 = xr[tid + 512];
    __shared__ float red[4];
    float s = v0 + v1 + v2;
    for (int off = 32; off; off >>= 1) s += __shfl_down(s, off);
    if ((tid & 63) == 0) red[tid >> 6] = s;
    __syncthreads();
    float mean = (red[0] + red[1] + red[2] + red[3]) * (1.f / 768.f);
    __syncthreads();
    float d0 = v0 - mean, d1 = v1 - mean, d2 = v2 - mean;
    s = d0 * d0 + d1 * d1 + d2 * d2;
    for (int off = 32; off; off >>= 1) s += __shfl_down(s, off);
    if ((tid & 63) == 0) red[tid >> 6] = s;
    __syncthreads();
    float var = (red[0] + red[1] + red[2] + red[3]) * (1.f / 768.f);
    float rs = rsqrtf(var + 1e-5f);
    float* yr = y + (size_t)row * DIM;
    yr[tid]       = d0 * rs * g[tid]       + bb[tid];
    yr[tid + 256] = d1 * rs * g[tid + 256] + bb[tid + 256];
    yr[tid + 512] = d2 * rs * g[tid + 512] + bb[tid + 512];
}

// Final LN over rows i>=10, f32 output (16,10,768)  [reference output dtype is float32]
__global__ __launch_bounds__(256) void lnf_k(const float* __restrict__ x, const float* __restrict__ g,
    const float* __restrict__ bb, float* __restrict__ out)
{
    int blk = blockIdx.x;
    int b = blk / 10, ii = blk - b * 10;
    int row = b * NSEQ + 10 + ii;
    const float* xr = x + (size_t)row * DIM;
    int tid = threadIdx.x;
    float v0 = xr[tid], v1 = xr[tid + 256], v2 = xr[tid + 512];
    __shared__ float red[4];
    float s = v0 + v1 + v2;
    for (int off = 32; off; off >>= 1) s += __shfl_down(s, off);
    if ((tid & 63) == 0) red[tid >> 6] = s;
    __syncthreads();
    float mean = (red[0] + red[1] + red[2] + red[3]) * (1.f / 768.f);
    __syncthreads();
    float d0 = v0 - mean, d1 = v1 - mean, d2 = v2 - mean;
    s = d0 * d0 + d1 * d1 + d2 * d2;
    for (int off = 32; off; off >>= 1) s += __shfl_down(s, off);
    if ((tid & 63) == 0) red[tid >> 6] = s;
    __syncthreads();
    float var = (red[0] + red[1] + red[2] + red[3]) * (1.f / 768.f);
    float rs = rsqrtf(var + 1e-5f);
    float* orow = out + ((size_t)(b * 10 + ii)) * DIM;
    orow[tid]       = d0 * rs * g[tid]       + bb[tid];
    orow[tid + 256] = d1 * rs * g[tid + 256] + bb[tid + 256];
    orow[tid + 512] = d2 * rs * g[tid + 512] + bb[tid + 512];
}

// ---------------------------------------------------------------- prefix rows
__global__ __launch_bounds__(256) void prefix_k(const float* __restrict__ p, float* __restrict__ t)
{
    int idx = blockIdx.x * 256 + threadIdx.x;
    if (idx < BB * 7680) {
        int b = idx / 7680;
        int r = idx - b * 7680;
        t[(size_t)b * (NSEQ * DIM) + 7680 + r] = p[r];
    }
}

// ---------------------------------------------------------------- local attention (non-mem layers)
__global__ __launch_bounds__(256) void lattn_k(const float* __restrict__ q, const float* __restrict__ kv,
    float* __restrict__ ao)
{
    int b = blockIdx.x, h = blockIdx.y;
    __shared__ float sims[NSEQ][NSEQ];
    __shared__ float probs[NSEQ][NSEQ];
    const float* qb = q + (size_t)b * NSEQ * DIM + h * DH;
    const float* kb = kv + (size_t)b * NSEQ * 192;
    int tid = threadIdx.x;
    for (int p = tid; p < NSEQ * NSEQ; p += 256) {
        int i = p / NSEQ, j = p - i * NSEQ;
        float s;
        if (j > i) s = -1.0e9f;
        else {
            s = 0.f;
            for (int d = 0; d < DH; d++) s = fmaf(qb[(size_t)i * DIM + d], kb[j * 192 + d], s);
        }
        sims[i][j] = s;
    }
    __syncthreads();
    if (tid < NSEQ) {
        int i = tid;
        float m = -1e30f;
        for (int j = 0; j < NSEQ; j++) m = fmaxf(m, sims[i][j]);
        float sum = 0.f;
        for (int j = 0; j < NSEQ; j++) { float e = expf(sims[i][j] - m); probs[i][j] = e; sum += e; }
        float inv = 1.f / sum;
        for (int j = 0; j < NSEQ; j++) probs[i][j] *= inv;
    }
    __syncthreads();
    for (int p = tid; p < NSEQ * DH; p += 256) {
        int i = p / DH, d = p - i * DH;
        float o = 0.f;
        for (int j = 0; j <= i; j++) o = fmaf(probs[i][j], kb[j * 192 + 96 + d], o);
        ao[((size_t)b * NSEQ + i) * DIM + h * DH + d] = o;
    }
}

// ---------------------------------------------------------------- mem top-k (per (chunk,h,b))
__global__ __launch_bounds__(256) void memtopk_k(const float* __restrict__ q, const float* __restrict__ memk,
    float* __restrict__ tkv, int* __restrict__ tki)
{
    int c = blockIdx.x, h = blockIdx.y, b = blockIdx.z;
    __shared__ float q_s[NSEQ][DH];
    __shared__ float sims[NSEQ][513];
    __shared__ float lv[NSEQ][32];
    __shared__ int   li[NSEQ][32];
    int tid = threadIdx.x;
    for (int idx = tid; idx < NSEQ * DH; idx += 256) {
        int i = idx / DH, d = idx - i * DH;
        q_s[i][d] = q[((size_t)b * NSEQ + i) * DIM + h * DH + d];
    }
    if (tid < NSEQ) {
        for (int j = 0; j < 32; j++) { lv[tid][j] = -1e30f; li[tid][j] = 0; }
    }
    __syncthreads();
    const float4* kb4 = (const float4*)(memk + (size_t)b * KMEM * DH);
    int k0base = c * CHUNK;
    for (int pass = 0; pass < CHUNK / 512; pass++) {
        int k0 = k0base + pass * 512;
        int ka = k0 + tid, kb = k0 + 256 + tid;
        float acc0[NSEQ], acc1[NSEQ];
#pragma unroll
        for (int i = 0; i < NSEQ; i++) { acc0[i] = 0.f; acc1[i] = 0.f; }
        for (int d4 = 0; d4 < 24; d4++) {
            float4 kva = kb4[(size_t)ka * 24 + d4];
            float4 kvb = kb4[(size_t)kb * 24 + d4];
#pragma unroll
            for (int i = 0; i < NSEQ; i++) {
                float4 qv = *(const float4*)&q_s[i][d4 * 4];
                acc0[i] += qv.x * kva.x + qv.y * kva.y + qv.z * kva.z + qv.w * kva.w;
                acc1[i] += qv.x * kvb.x + qv.y * kvb.y + qv.z * kvb.z + qv.w * kvb.w;
            }
        }
#pragma unroll
        for (int i = 0; i < NSEQ; i++) { sims[i][tid] = acc0[i]; sims[i][256 + tid] = acc1[i]; }
        __syncthreads();
        if (tid < NSEQ) {
            int i = tid;
            float vmin = lv[i][31];
            for (int j = 0; j < 512; j++) {
                float s = sims[i][j];
                if (s > vmin) {
                    int pos = 31;
                    while (pos > 0 && lv[i][pos - 1] < s) {
                        lv[i][pos] = lv[i][pos - 1]; li[i][pos] = li[i][pos - 1];
                        pos--;
                    }
                    lv[i][pos] = s; li[i][pos] = k0 + j;
                    vmin = lv[i][31];
                }
            }
        }
        __syncthreads();
    }
    if (tid < NSEQ) {
        size_t base = ((((size_t)b * HEADS + h) * NSEQ + tid) * NCHUNK + c) * 32;
        for (int j = 0; j < 32; j++) { tkv[base + j] = lv[tid][j]; tki[base + j] = li[tid][j]; }
    }
}

// ---------------------------------------------------------------- mem attention merge (per (i,h,b))
__global__ __launch_bounds__(64) void memattn_k(const float* __restrict__ q, const float* __restrict__ kv,
    const float* __restrict__ memv, const float* __restrict__ tkv, const int* __restrict__ tki,
    float* __restrict__ ao)
{
    int i = blockIdx.x, h = blockIdx.y, b = blockIdx.z;
    __shared__ float cv[128];
    __shared__ int   ci[128];
    __shared__ float selv[32];
    __shared__ int   seli[32];
    __shared__ float ls[NSEQ];
    __shared__ float probs[52];
    int tid = threadIdx.x;
    size_t base = (((size_t)b * HEADS + h) * NSEQ + i) * (NCHUNK * 32);
    cv[tid] = tkv[base + tid];           ci[tid] = tki[base + tid];
    cv[64 + tid] = tkv[base + 64 + tid]; ci[64 + tid] = tki[base + 64 + tid];
    const float* qr = q + ((size_t)b * NSEQ + i) * DIM + h * DH;
    const float* kvb = kv + (size_t)b * NSEQ * 192;
    if (tid <= i) {
        float s = 0.f;
        for (int d = 0; d < DH; d++) s = fmaf(qr[d], kvb[tid * 192 + d], s);
        ls[tid] = s;
    }
    __syncthreads();
    for (int r = 0; r < 32; r++) {
        float v0 = cv[tid], v1 = cv[64 + tid];
        int i0 = ci[tid], i1 = ci[64 + tid];
        bool take1 = (v1 > v0) || (v1 == v0 && i1 < i0);
        float bv = take1 ? v1 : v0;
        int bidx = take1 ? i1 : i0;
        int bs = take1 ? (64 + tid) : tid;
        for (int off = 32; off; off >>= 1) {
            float ov = __shfl_down(bv, off);
            int oi = __shfl_down(bidx, off);
            int os = __shfl_down(bs, off);
            if (ov > bv || (ov == bv && oi < bidx)) { bv = ov; bidx = oi; bs = os; }
        }
        if (tid == 0) { selv[r] = bv; seli[r] = bidx; cv[bs] = -1e30f; }
        __syncthreads();
    }
    if (tid == 0) {
        float m = -1e30f;
        for (int r = 0; r < 32; r++) m = fmaxf(m, selv[r]);
        for (int j = 0; j <= i; j++) m = fmaxf(m, ls[j]);
        float sum = 0.f;
        for (int r = 0; r < 32; r++) { float e = expf(selv[r] - m); probs[r] = e; sum += e; }
        for (int j = 0; j <= i; j++) { float e = expf(ls[j] - m); probs[32 + j] = e; sum += e; }
        float inv = 1.f / sum;
        for (int r = 0; r < 32 + i + 1; r++) probs[r] *= inv;
    }
    __syncthreads();
    const float* mvb = memv + (size_t)b * KMEM * DH;
    for (int d = tid; d < DH; d += 64) {
        float o = 0.f;
        for (int r = 0; r < 32; r++) o = fmaf(probs[r], mvb[(size_t)seli[r] * DH + d], o);
        for (int j = 0; j <= i; j++) o = fmaf(probs[32 + j], kvb[j * 192 + 96 + d], o);
        ao[((size_t)b * NSEQ + i) * DIM + h * DH + d] = o;
    }
}

// ---------------------------------------------------------------- host
extern "C" void kernel_launch(void* const* d_in, const int* in_sizes, int n_in,
                              void* d_out, int out_size, void* d_ws, size_t ws_size,
                              hipStream_t stream) {
    const float* x            = (const float*)d_in[0];
    const float* linear_w     = (const float*)d_in[1];
    const float* linear_b     = (const float*)d_in[2];
    const float* prefix_const = (const float*)d_in[3];
    const float* ln1_g        = (const float*)d_in[4];
    const float* ln1_b        = (const float*)d_in[5];
    const float* wq           = (const float*)d_in[6];
    const float* wkv          = (const float*)d_in[7];
    const float* wo           = (const float*)d_in[8];
    const float* ln2_g        = (const float*)d_in[9];
    const float* ln2_b        = (const float*)d_in[10];
    const float* w1           = (const float*)d_in[11];
    const float* b1           = (const float*)d_in[12];
    const float* w2           = (const float*)d_in[13];
    const float* b2           = (const float*)d_in[14];
    const float* lnf_g        = (const float*)d_in[15];
    const float* lnf_b        = (const float*)d_in[16];
    const float* mem_k        = (const float*)d_in[17];
    const float* mem_v        = (const float*)d_in[18];

    float* ws = (float*)d_ws;
    float* t   = ws;                   // 320*768   = 245760
    float* y   = ws + 245760;
    float* qb  = ws + 491520;
    float* kvb = ws + 737280;          // 320*192   = 61440
    float* ao  = ws + 798720;
    float* h1  = ws + 1044480;         // 320*3072  = 983040
    float* tkv = ws + 2027520;         // 327680
    int*   tki = (int*)(ws + 2355200); // 327680
    float* out = (float*)d_out;

    const float qscale = 0.10206207261596577f; // 96^-0.5

    gemm_k<<<dim3(120, 1), 256, 0, stream>>>(x, linear_w, linear_b, nullptr, t,
                                             16, 7680, 640, 640, 15360, 1.f, 0);
    prefix_k<<<dim3(480), 256, 0, stream>>>(prefix_const, t);

    for (int l = 0; l < 8; l++) {
        ln_k<<<320, 256, 0, stream>>>(t, ln1_g + (size_t)l * DIM, ln1_b + (size_t)l * DIM, y);
        gemm_k<<<dim3(12, 20), 256, 0, stream>>>(y, wq + (size_t)l * DIM * DIM, nullptr, nullptr, qb,
                                                 320, 768, 768, 768, 768, qscale, 0);
        gemm_k<<<dim3(3, 20), 256, 0, stream>>>(y, wkv + (size_t)l * DIM * 192, nullptr, nullptr, kvb,
                                                320, 192, 768, 768, 192, 1.f, 0);
        if (l == 4 || l == 5) {
            memtopk_k<<<dim3(NCHUNK, HEADS, BB), 256, 0, stream>>>(qb, mem_k, tkv, tki);
            memattn_k<<<dim3(NSEQ, HEADS, BB), 64, 0, stream>>>(qb, kvb, mem_v, tkv, tki, ao);
        } else {
            lattn_k<<<dim3(BB, HEADS), 256, 0, stream>>>(qb, kvb, ao);
        }
        gemm_k<<<dim3(12, 20), 256, 0, stream>>>(ao, wo + (size_t)l * DIM * DIM, nullptr, t, t,
                                                 320, 768, 768, 768, 768, 1.f, 0);
        ln_k<<<320, 256, 0, stream>>>(t, ln2_g + (size_t)l * DIM, ln2_b + (size_t)l * DIM, y);
        gemm_k<<<dim3(48, 20), 256, 0, stream>>>(y, w1 + (size_t)l * DIM * FF, b1 + (size_t)l * FF, nullptr, h1,
                                                 320, 3072, 768, 768, 3072, 1.f, 1);
        gemm_k<<<dim3(12, 20), 256, 0, stream>>>(h1, w2 + (size_t)l * FF * DIM, b2 + (size_t)l * DIM, t, t,
                                                 320, 768, 3072, 3072, 768, 1.f, 0);
    }
    lnf_k<<<160, 256, 0, stream>>>(t, lnf_g, lnf_b, out);
}

// Round 3
// 6989.552 us; speedup vs baseline: 1.5302x; 1.5302x over previous
//
#include <hip/hip_runtime.h>
#include <hip/hip_bf16.h>

// Sizes
#define BB 16
#define NSEQ 20
#define HEADS 8
#define DH 96
#define DIM 768
#define FF 3072
#define KMEM 32768
#define NCHUNK 4
#define CHUNK 8192
#define KCHUNK 512
#define CAP 128

// ---------------------------------------------------------------- GEMM
// C[m][n] = act(scale * sum_k A[m][k]*B[k][n] + bias[n]) + resid[m][n]
__global__ __launch_bounds__(256) void gemm_k(const float* __restrict__ A, const float* __restrict__ B,
    const float* __restrict__ bias, const float* __restrict__ resid, float* __restrict__ C,
    int M, int N, int K, int lda, int ldc, float scale, int act)
{
    __shared__ float a_sh[16 * KCHUNK];
    __shared__ float red[4 * 16 * 64];
    int tid = threadIdx.x;
    int n0 = blockIdx.x * 64;
    int m0 = blockIdx.y * 16;
    int lane_n = tid & 63;
    int slice = tid >> 6;
    int n = n0 + lane_n;
    float acc[16];
#pragma unroll
    for (int mi = 0; mi < 16; mi++) acc[mi] = 0.f;
    for (int kc = 0; kc < K; kc += KCHUNK) {
        int kl = min(KCHUNK, K - kc);
        for (int idx = tid; idx < 16 * kl; idx += 256) {
            int mi = idx / kl, kk = idx - mi * kl;
            a_sh[mi * KCHUNK + kk] = A[(size_t)(m0 + mi) * lda + kc + kk];
        }
        __syncthreads();
        if (n < N) {
            for (int k = slice; k < kl; k += 4) {
                float bv = B[(size_t)(kc + k) * N + n];
#pragma unroll
                for (int mi = 0; mi < 16; mi++) acc[mi] = fmaf(a_sh[mi * KCHUNK + k], bv, acc[mi]);
            }
        }
        __syncthreads();
    }
#pragma unroll
    for (int mi = 0; mi < 16; mi++) red[(slice * 16 + mi) * 64 + lane_n] = acc[mi];
    __syncthreads();
#pragma unroll
    for (int p = 0; p < 4; p++) {
        int idx = tid + p * 256;
        int mi = idx >> 6, nl = idx & 63;
        int nn = n0 + nl;
        if (nn < N) {
            float v = red[(0 * 16 + mi) * 64 + nl] + red[(1 * 16 + mi) * 64 + nl]
                    + red[(2 * 16 + mi) * 64 + nl] + red[(3 * 16 + mi) * 64 + nl];
            v *= scale;
            if (bias) v += bias[nn];
            if (act) {
                float xx = v;
                float tt = 0.7978845608028654f * (xx + 0.044715f * xx * xx * xx);
                v = 0.5f * xx * (1.0f + tanhf(tt));
            }
            if (resid) v += resid[(size_t)(m0 + mi) * ldc + nn];
            C[(size_t)(m0 + mi) * ldc + nn] = v;
        }
    }
}

// ---------------------------------------------------------------- LayerNorm
__global__ __launch_bounds__(256) void ln_k(const float* __restrict__ x, const float* __restrict__ g,
    const float* __restrict__ bb, float* __restrict__ y)
{
    int row = blockIdx.x;
    const float* xr = x + (size_t)row * DIM;
    int tid = threadIdx.x;
    float v0 = xr[tid], v1 = xr[tid + 256], v2 = xr[tid + 512];
    __shared__ float red[4];
    float s = v0 + v1 + v2;
    for (int off = 32; off; off >>= 1) s += __shfl_down(s, off);
    if ((tid & 63) == 0) red[tid >> 6] = s;
    __syncthreads();
    float mean = (red[0] + red[1] + red[2] + red[3]) * (1.f / 768.f);
    __syncthreads();
    float d0 = v0 - mean, d1 = v1 - mean, d2 = v2 - mean;
    s = d0 * d0 + d1 * d1 + d2 * d2;
    for (int off = 32; off; off >>= 1) s += __shfl_down(s, off);
    if ((tid & 63) == 0) red[tid >> 6] = s;
    __syncthreads();
    float var = (red[0] + red[1] + red[2] + red[3]) * (1.f / 768.f);
    float rs = rsqrtf(var + 1e-5f);
    float* yr = y + (size_t)row * DIM;
    yr[tid]       = d0 * rs * g[tid]       + bb[tid];
    yr[tid + 256] = d1 * rs * g[tid + 256] + bb[tid + 256];
    yr[tid + 512] = d2 * rs * g[tid + 512] + bb[tid + 512];
}

// Final LN over rows i>=10, f32 output (16,10,768)
__global__ __launch_bounds__(256) void lnf_k(const float* __restrict__ x, const float* __restrict__ g,
    const float* __restrict__ bb, float* __restrict__ out)
{
    int blk = blockIdx.x;
    int b = blk / 10, ii = blk - b * 10;
    int row = b * NSEQ + 10 + ii;
    const float* xr = x + (size_t)row * DIM;
    int tid = threadIdx.x;
    float v0 = xr[tid], v1 = xr[tid + 256], v2 = xr[tid + 512];
    __shared__ float red[4];
    float s = v0 + v1 + v2;
    for (int off = 32; off; off >>= 1) s += __shfl_down(s, off);
    if ((tid & 63) == 0) red[tid >> 6] = s;
    __syncthreads();
    float mean = (red[0] + red[1] + red[2] + red[3]) * (1.f / 768.f);
    __syncthreads();
    float d0 = v0 - mean, d1 = v1 - mean, d2 = v2 - mean;
    s = d0 * d0 + d1 * d1 + d2 * d2;
    for (int off = 32; off; off >>= 1) s += __shfl_down(s, off);
    if ((tid & 63) == 0) red[tid >> 6] = s;
    __syncthreads();
    float var = (red[0] + red[1] + red[2] + red[3]) * (1.f / 768.f);
    float rs = rsqrtf(var + 1e-5f);
    float* orow = out + ((size_t)(b * 10 + ii)) * DIM;
    orow[tid]       = d0 * rs * g[tid]       + bb[tid];
    orow[tid + 256] = d1 * rs * g[tid + 256] + bb[tid + 256];
    orow[tid + 512] = d2 * rs * g[tid + 512] + bb[tid + 512];
}

// ---------------------------------------------------------------- prefix rows
__global__ __launch_bounds__(256) void prefix_k(const float* __restrict__ p, float* __restrict__ t)
{
    int idx = blockIdx.x * 256 + threadIdx.x;
    if (idx < BB * 7680) {
        int b = idx / 7680;
        int r = idx - b * 7680;
        t[(size_t)b * (NSEQ * DIM) + 7680 + r] = p[r];
    }
}

// ---------------------------------------------------------------- local attention
__global__ __launch_bounds__(256) void lattn_k(const float* __restrict__ q, const float* __restrict__ kv,
    float* __restrict__ ao)
{
    int b = blockIdx.x, h = blockIdx.y;
    __shared__ float sims[NSEQ][NSEQ];
    __shared__ float probs[NSEQ][NSEQ];
    const float* qb = q + (size_t)b * NSEQ * DIM + h * DH;
    const float* kb = kv + (size_t)b * NSEQ * 192;
    int tid = threadIdx.x;
    for (int p = tid; p < NSEQ * NSEQ; p += 256) {
        int i = p / NSEQ, j = p - i * NSEQ;
        float s;
        if (j > i) s = -1.0e9f;
        else {
            s = 0.f;
            for (int d = 0; d < DH; d++) s = fmaf(qb[(size_t)i * DIM + d], kb[j * 192 + d], s);
        }
        sims[i][j] = s;
    }
    __syncthreads();
    if (tid < NSEQ) {
        int i = tid;
        float m = -1e30f;
        for (int j = 0; j < NSEQ; j++) m = fmaxf(m, sims[i][j]);
        float sum = 0.f;
        for (int j = 0; j < NSEQ; j++) { float e = expf(sims[i][j] - m); probs[i][j] = e; sum += e; }
        float inv = 1.f / sum;
        for (int j = 0; j < NSEQ; j++) probs[i][j] *= inv;
    }
    __syncthreads();
    for (int p = tid; p < NSEQ * DH; p += 256) {
        int i = p / DH, d = p - i * DH;
        float o = 0.f;
        for (int j = 0; j <= i; j++) o = fmaf(probs[i][j], kb[j * 192 + 96 + d], o);
        ao[((size_t)b * NSEQ + i) * DIM + h * DH + d] = o;
    }
}

// ---------------------------------------------------------------- top-k helpers
__device__ __forceinline__ bool tk_better(float va, int ia, float vb, int ib) {
    return (va > vb) || (va == vb && ia < ib);
}

__device__ __forceinline__ void lds_fence() {
    asm volatile("s_waitcnt lgkmcnt(0)" ::: "memory");
    __builtin_amdgcn_sched_barrier(0);
}

// Exact top-32 of buf[0..cnt) by (value desc, idx asc). Bitonic-128 in regs.
// Writes survivors to slots 0..31, returns lane's rank-`lane` element in (v0,i0),
// thr_out = rank-31 value. Single-wave, no cross-wave access.
__device__ void topk32(float* bv, int* bi, int cnt, int lane,
                       float& ov, int& oi, float& thr_out) {
    lds_fence();
    float v0 = (lane < cnt)      ? bv[lane]      : -3.0e38f;
    int   i0 = (lane < cnt)      ? bi[lane]      : 0x7fffffff;
    float v1 = (lane + 64 < cnt) ? bv[lane + 64] : -3.0e38f;
    int   i1 = (lane + 64 < cnt) ? bi[lane + 64] : 0x7fffffff;
    lds_fence();
#pragma unroll
    for (int k = 2; k <= 128; k <<= 1) {
#pragma unroll
        for (int j = 64; j >= 1; j >>= 1) {
            if (j >= k) continue;
            if (j == 64) {
                // partner is the other reg, same lane; e0=lane (first), e1=lane+64
                bool asc = ((lane & k) == 0);     // k==128 here -> true
                bool b01 = tk_better(v0, i0, v1, i1);
                if (b01 != asc) { float tv = v0; int ti = i0; v0 = v1; i0 = i1; v1 = tv; i1 = ti; }
            } else {
                {
                    float pv = __shfl_xor(v0, j); int pi = __shfl_xor(i0, j);
                    bool asc = ((lane & k) == 0);
                    bool first = ((lane & j) == 0);
                    bool mb = tk_better(v0, i0, pv, pi);
                    bool keep = first ? (mb == asc) : (mb != asc);
                    if (!keep) { v0 = pv; i0 = pi; }
                }
                {
                    float pv = __shfl_xor(v1, j); int pi = __shfl_xor(i1, j);
                    bool asc = (((lane + 64) & k) == 0);
                    bool first = ((lane & j) == 0);
                    bool mb = tk_better(v1, i1, pv, pi);
                    bool keep = first ? (mb == asc) : (mb != asc);
                    if (!keep) { v1 = pv; i1 = pi; }
                }
            }
        }
    }
    if (lane < 32) { bv[lane] = v0; bi[lane] = i0; }
    lds_fence();
    ov = v0; oi = i0;
    thr_out = __shfl(v0, 31);
}

// ---------------------------------------------------------------- mem top-k v2
// Block (c,h,b), 256 thr = 4 waves. Wave w owns rows 5w..5w+4.
// Lane = (key kk = lane>>2) x (dim-quarter qt = lane&3). Q cached in regs.
// Wave-parallel ballot-append into per-row LDS candidate buffer + bitonic compaction.
__global__ __launch_bounds__(256) void memtopk_k(const float* __restrict__ q, const float* __restrict__ memk,
    float* __restrict__ tkv, int* __restrict__ tki)
{
    __shared__ float bufv[NSEQ][CAP];
    __shared__ int   bufi[NSEQ][CAP];
    int c = blockIdx.x, h = blockIdx.y, b = blockIdx.z;
    int tid = threadIdx.x;
    int lane = tid & 63;
    int w = tid >> 6;
    int r0 = w * 5;
    int qt = lane & 3;
    int kk = lane >> 2;

    float4 qreg[5][6];
#pragma unroll
    for (int rr = 0; rr < 5; rr++) {
        const float4* qrow = (const float4*)(q + ((size_t)(b * NSEQ + r0 + rr)) * DIM + h * DH + qt * 24);
#pragma unroll
        for (int i = 0; i < 6; i++) qreg[rr][i] = qrow[i];
    }

    float thrR[5]; int cntR[5];
#pragma unroll
    for (int rr = 0; rr < 5; rr++) { thrR[rr] = -3.0e38f; cntR[rr] = 0; }

    const float* kb = memk + (size_t)b * KMEM * DH;
    int k0 = c * CHUNK;

    for (int p = 0; p < CHUNK / 16; p++) {
        int key = k0 + p * 16 + kk;
        const float4* krow = (const float4*)(kb + (size_t)key * DH + qt * 24);
        float a[5];
#pragma unroll
        for (int rr = 0; rr < 5; rr++) a[rr] = 0.f;
#pragma unroll
        for (int i = 0; i < 6; i++) {
            float4 kv = krow[i];
#pragma unroll
            for (int rr = 0; rr < 5; rr++) {
                float4 qv = qreg[rr][i];
                a[rr] = fmaf(qv.x, kv.x, a[rr]);
                a[rr] = fmaf(qv.y, kv.y, a[rr]);
                a[rr] = fmaf(qv.z, kv.z, a[rr]);
                a[rr] = fmaf(qv.w, kv.w, a[rr]);
            }
        }
#pragma unroll
        for (int rr = 0; rr < 5; rr++) {
            a[rr] += __shfl_xor(a[rr], 1);
            a[rr] += __shfl_xor(a[rr], 2);
        }
#pragma unroll
        for (int rr = 0; rr < 5; rr++) {
            bool cand = (qt == 0) && (a[rr] >= thrR[rr]);
            unsigned long long mask = __ballot(cand);
            int n = __popcll(mask);
            if (n) {
                int r = r0 + rr;
                if (cntR[rr] + n > CAP) {
                    float dv; int di;
                    topk32(&bufv[r][0], &bufi[r][0], cntR[rr], lane, dv, di, thrR[rr]);
                    cntR[rr] = 32;
                }
                int pos = cntR[rr] + __popcll(mask & ((1ull << lane) - 1ull));
                if (cand) { bufv[r][pos] = a[rr]; bufi[r][pos] = key; }
                cntR[rr] += n;
            }
        }
    }
#pragma unroll
    for (int rr = 0; rr < 5; rr++) {
        int r = r0 + rr;
        float ov; int oi; float dthr;
        topk32(&bufv[r][0], &bufi[r][0], cntR[rr], lane, ov, oi, dthr);
        if (lane < 32) {
            size_t base = ((((size_t)b * HEADS + h) * NSEQ + r) * NCHUNK + c) * 32;
            tkv[base + lane] = ov;
            tki[base + lane] = oi;
        }
    }
}

// ---------------------------------------------------------------- mem attention merge (per (i,h,b))
__global__ __launch_bounds__(64) void memattn_k(const float* __restrict__ q, const float* __restrict__ kv,
    const float* __restrict__ memv, const float* __restrict__ tkv, const int* __restrict__ tki,
    float* __restrict__ ao)
{
    int i = blockIdx.x, h = blockIdx.y, b = blockIdx.z;
    __shared__ float cv[128];
    __shared__ int   ci[128];
    __shared__ float selv[32];
    __shared__ int   seli[32];
    __shared__ float ls[NSEQ];
    __shared__ float probs[52];
    int tid = threadIdx.x;
    size_t base = (((size_t)b * HEADS + h) * NSEQ + i) * (NCHUNK * 32);
    cv[tid] = tkv[base + tid];           ci[tid] = tki[base + tid];
    cv[64 + tid] = tkv[base + 64 + tid]; ci[64 + tid] = tki[base + 64 + tid];
    const float* qr = q + ((size_t)b * NSEQ + i) * DIM + h * DH;
    const float* kvb = kv + (size_t)b * NSEQ * 192;
    if (tid <= i) {
        float s = 0.f;
        for (int d = 0; d < DH; d++) s = fmaf(qr[d], kvb[tid * 192 + d], s);
        ls[tid] = s;
    }
    __syncthreads();
    for (int r = 0; r < 32; r++) {
        float v0 = cv[tid], v1 = cv[64 + tid];
        int i0 = ci[tid], i1 = ci[64 + tid];
        bool take1 = (v1 > v0) || (v1 == v0 && i1 < i0);
        float bv = take1 ? v1 : v0;
        int bidx = take1 ? i1 : i0;
        int bs = take1 ? (64 + tid) : tid;
        for (int off = 32; off; off >>= 1) {
            float ovv = __shfl_down(bv, off);
            int oii = __shfl_down(bidx, off);
            int oss = __shfl_down(bs, off);
            if (ovv > bv || (ovv == bv && oii < bidx)) { bv = ovv; bidx = oii; bs = oss; }
        }
        if (tid == 0) { selv[r] = bv; seli[r] = bidx; cv[bs] = -1e30f; }
        __syncthreads();
    }
    if (tid == 0) {
        float m = -1e30f;
        for (int r = 0; r < 32; r++) m = fmaxf(m, selv[r]);
        for (int j = 0; j <= i; j++) m = fmaxf(m, ls[j]);
        float sum = 0.f;
        for (int r = 0; r < 32; r++) { float e = expf(selv[r] - m); probs[r] = e; sum += e; }
        for (int j = 0; j <= i; j++) { float e = expf(ls[j] - m); probs[32 + j] = e; sum += e; }
        float inv = 1.f / sum;
        for (int r = 0; r < 32 + i + 1; r++) probs[r] *= inv;
    }
    __syncthreads();
    const float* mvb = memv + (size_t)b * KMEM * DH;
    for (int d = tid; d < DH; d += 64) {
        float o = 0.f;
        for (int r = 0; r < 32; r++) o = fmaf(probs[r], mvb[(size_t)seli[r] * DH + d], o);
        for (int j = 0; j <= i; j++) o = fmaf(probs[32 + j], kvb[j * 192 + 96 + d], o);
        ao[((size_t)b * NSEQ + i) * DIM + h * DH + d] = o;
    }
}

// ---------------------------------------------------------------- host
extern "C" void kernel_launch(void* const* d_in, const int* in_sizes, int n_in,
                              void* d_out, int out_size, void* d_ws, size_t ws_size,
                              hipStream_t stream) {
    const float* x            = (const float*)d_in[0];
    const float* linear_w     = (const float*)d_in[1];
    const float* linear_b     = (const float*)d_in[2];
    const float* prefix_const = (const float*)d_in[3];
    const float* ln1_g        = (const float*)d_in[4];
    const float* ln1_b        = (const float*)d_in[5];
    const float* wq           = (const float*)d_in[6];
    const float* wkv          = (const float*)d_in[7];
    const float* wo           = (const float*)d_in[8];
    const float* ln2_g        = (const float*)d_in[9];
    const float* ln2_b        = (const float*)d_in[10];
    const float* w1           = (const float*)d_in[11];
    const float* b1           = (const float*)d_in[12];
    const float* w2           = (const float*)d_in[13];
    const float* b2           = (const float*)d_in[14];
    const float* lnf_g        = (const float*)d_in[15];
    const float* lnf_b        = (const float*)d_in[16];
    const float* mem_k        = (const float*)d_in[17];
    const float* mem_v        = (const float*)d_in[18];

    float* ws = (float*)d_ws;
    float* t   = ws;                   // 320*768
    float* y   = ws + 245760;
    float* qb  = ws + 491520;
    float* kvb = ws + 737280;          // 320*192
    float* ao  = ws + 798720;
    float* h1  = ws + 1044480;         // 320*3072
    float* tkv = ws + 2027520;         // 327680
    int*   tki = (int*)(ws + 2355200); // 327680
    float* out = (float*)d_out;

    const float qscale = 0.10206207261596577f; // 96^-0.5

    gemm_k<<<dim3(120, 1), 256, 0, stream>>>(x, linear_w, linear_b, nullptr, t,
                                             16, 7680, 640, 640, 15360, 1.f, 0);
    prefix_k<<<dim3(480), 256, 0, stream>>>(prefix_const, t);

    for (int l = 0; l < 8; l++) {
        ln_k<<<320, 256, 0, stream>>>(t, ln1_g + (size_t)l * DIM, ln1_b + (size_t)l * DIM, y);
        gemm_k<<<dim3(12, 20), 256, 0, stream>>>(y, wq + (size_t)l * DIM * DIM, nullptr, nullptr, qb,
                                                 320, 768, 768, 768, 768, qscale, 0);
        gemm_k<<<dim3(3, 20), 256, 0, stream>>>(y, wkv + (size_t)l * DIM * 192, nullptr, nullptr, kvb,
                                                320, 192, 768, 768, 192, 1.f, 0);
        if (l == 4 || l == 5) {
            memtopk_k<<<dim3(NCHUNK, HEADS, BB), 256, 0, stream>>>(qb, mem_k, tkv, tki);
            memattn_k<<<dim3(NSEQ, HEADS, BB), 64, 0, stream>>>(qb, kvb, mem_v, tkv, tki, ao);
        } else {
            lattn_k<<<dim3(BB, HEADS), 256, 0, stream>>>(qb, kvb, ao);
        }
        gemm_k<<<dim3(12, 20), 256, 0, stream>>>(ao, wo + (size_t)l * DIM * DIM, nullptr, t, t,
                                                 320, 768, 768, 768, 768, 1.f, 0);
        ln_k<<<320, 256, 0, stream>>>(t, ln2_g + (size_t)l * DIM, ln2_b + (size_t)l * DIM, y);
        gemm_k<<<dim3(48, 20), 256, 0, stream>>>(y, w1 + (size_t)l * DIM * FF, b1 + (size_t)l * FF, nullptr, h1,
                                                 320, 3072, 768, 768, 3072, 1.f, 1);
        gemm_k<<<dim3(12, 20), 256, 0, stream>>>(h1, w2 + (size_t)l * FF * DIM, b2 + (size_t)l * DIM, t, t,
                                                 320, 768, 3072, 3072, 768, 1.f, 0);
    }
    lnf_k<<<160, 256, 0, stream>>>(t, lnf_g, lnf_b, out);
}

// Round 4
// 2775.489 us; speedup vs baseline: 3.8536x; 2.5183x over previous
//
#include <hip/hip_runtime.h>
#include <hip/hip_bf16.h>

// Sizes
#define BB 16
#define NSEQ 20
#define HEADS 8
#define DH 96
#define DIM 768
#define FF 3072
#define KMEM 32768
#define NCHUNK 8
#define CHUNK 4096
#define CAP 128

typedef __attribute__((ext_vector_type(8))) short short8v;
typedef __attribute__((ext_vector_type(4))) float f32x4;

__device__ __forceinline__ short f2b(float x) {
    __hip_bfloat16 h = __float2bfloat16(x);
    return *reinterpret_cast<short*>(&h);
}

// ---------------------------------------------------------------- MFMA GEMM
// C[m][n] = act(scale * sum_k A[m][k]*B[k][n] + bias[n]) + resid[m][n]
// f32 in/out, bf16 MFMA compute. Block = 256 thr = 4 waves; wave w owns a
// 16x32 tile at cols n0 + w*32; grid = (ceil(N/128), M/16). M % 16 == 0.
__global__ __launch_bounds__(256) void gemm_mfma(const float* __restrict__ A, const float* __restrict__ B,
    const float* __restrict__ bias, const float* __restrict__ resid, float* __restrict__ C,
    int M, int N, int K, int lda, int ldc, float scale, int act)
{
    int tid = threadIdx.x;
    int w = tid >> 6, lane = tid & 63;
    int m0 = blockIdx.y * 16;
    int n0 = blockIdx.x * 128 + w * 32;
    int row = lane & 15;      // A row within tile; also frag col offset
    int kg  = lane >> 4;      // 0..3 k-group
    const float* arow = A + (size_t)(m0 + row) * lda;
    int c0 = n0 + row;
    int c1 = n0 + 16 + row;
    int c0c = min(c0, N - 1);
    int c1c = min(c1, N - 1);
    f32x4 acc0 = {0.f, 0.f, 0.f, 0.f};
    f32x4 acc1 = {0.f, 0.f, 0.f, 0.f};

    for (int k0 = 0; k0 < K; k0 += 32) {
        int kb = k0 + kg * 8;
        float av[8];
        *(float4*)(av)     = *(const float4*)(arow + kb);
        *(float4*)(av + 4) = *(const float4*)(arow + kb + 4);
        const float* bp0 = B + c0c;
        const float* bp1 = B + c1c;
        float bv0[8], bv1[8];
#pragma unroll
        for (int j = 0; j < 8; j++) {
            bv0[j] = bp0[(size_t)(kb + j) * N];
            bv1[j] = bp1[(size_t)(kb + j) * N];
        }
        short8v af, b0f, b1f;
#pragma unroll
        for (int j = 0; j < 8; j++) {
            af[j]  = f2b(av[j]);
            b0f[j] = f2b(bv0[j]);
            b1f[j] = f2b(bv1[j]);
        }
        acc0 = __builtin_amdgcn_mfma_f32_16x16x32_bf16(af, b0f, acc0, 0, 0, 0);
        acc1 = __builtin_amdgcn_mfma_f32_16x16x32_bf16(af, b1f, acc1, 0, 0, 0);
    }

#pragma unroll
    for (int r = 0; r < 4; r++) {
        int rw = m0 + kg * 4 + r;
        if (c0 < N) {
            float v = acc0[r] * scale;
            if (bias) v += bias[c0];
            if (act) {
                float xx = v;
                float tt = 0.7978845608028654f * (xx + 0.044715f * xx * xx * xx);
                v = 0.5f * xx * (1.0f + tanhf(tt));
            }
            if (resid) v += resid[(size_t)rw * ldc + c0];
            C[(size_t)rw * ldc + c0] = v;
        }
        if (c1 < N) {
            float v = acc1[r] * scale;
            if (bias) v += bias[c1];
            if (act) {
                float xx = v;
                float tt = 0.7978845608028654f * (xx + 0.044715f * xx * xx * xx);
                v = 0.5f * xx * (1.0f + tanhf(tt));
            }
            if (resid) v += resid[(size_t)rw * ldc + c1];
            C[(size_t)rw * ldc + c1] = v;
        }
    }
}

// ---------------------------------------------------------------- LayerNorm
__global__ __launch_bounds__(256) void ln_k(const float* __restrict__ x, const float* __restrict__ g,
    const float* __restrict__ bb, float* __restrict__ y)
{
    int row = blockIdx.x;
    const float* xr = x + (size_t)row * DIM;
    int tid = threadIdx.x;
    float v0 = xr[tid], v1 = xr[tid + 256], v2 = xr[tid + 512];
    __shared__ float red[4];
    float s = v0 + v1 + v2;
    for (int off = 32; off; off >>= 1) s += __shfl_down(s, off);
    if ((tid & 63) == 0) red[tid >> 6] = s;
    __syncthreads();
    float mean = (red[0] + red[1] + red[2] + red[3]) * (1.f / 768.f);
    __syncthreads();
    float d0 = v0 - mean, d1 = v1 - mean, d2 = v2 - mean;
    s = d0 * d0 + d1 * d1 + d2 * d2;
    for (int off = 32; off; off >>= 1) s += __shfl_down(s, off);
    if ((tid & 63) == 0) red[tid >> 6] = s;
    __syncthreads();
    float var = (red[0] + red[1] + red[2] + red[3]) * (1.f / 768.f);
    float rs = rsqrtf(var + 1e-5f);
    float* yr = y + (size_t)row * DIM;
    yr[tid]       = d0 * rs * g[tid]       + bb[tid];
    yr[tid + 256] = d1 * rs * g[tid + 256] + bb[tid + 256];
    yr[tid + 512] = d2 * rs * g[tid + 512] + bb[tid + 512];
}

// Final LN over rows i>=10, f32 output (16,10,768)
__global__ __launch_bounds__(256) void lnf_k(const float* __restrict__ x, const float* __restrict__ g,
    const float* __restrict__ bb, float* __restrict__ out)
{
    int blk = blockIdx.x;
    int b = blk / 10, ii = blk - b * 10;
    int row = b * NSEQ + 10 + ii;
    const float* xr = x + (size_t)row * DIM;
    int tid = threadIdx.x;
    float v0 = xr[tid], v1 = xr[tid + 256], v2 = xr[tid + 512];
    __shared__ float red[4];
    float s = v0 + v1 + v2;
    for (int off = 32; off; off >>= 1) s += __shfl_down(s, off);
    if ((tid & 63) == 0) red[tid >> 6] = s;
    __syncthreads();
    float mean = (red[0] + red[1] + red[2] + red[3]) * (1.f / 768.f);
    __syncthreads();
    float d0 = v0 - mean, d1 = v1 - mean, d2 = v2 - mean;
    s = d0 * d0 + d1 * d1 + d2 * d2;
    for (int off = 32; off; off >>= 1) s += __shfl_down(s, off);
    if ((tid & 63) == 0) red[tid >> 6] = s;
    __syncthreads();
    float var = (red[0] + red[1] + red[2] + red[3]) * (1.f / 768.f);
    float rs = rsqrtf(var + 1e-5f);
    float* orow = out + ((size_t)(b * 10 + ii)) * DIM;
    orow[tid]       = d0 * rs * g[tid]       + bb[tid];
    orow[tid + 256] = d1 * rs * g[tid + 256] + bb[tid + 256];
    orow[tid + 512] = d2 * rs * g[tid + 512] + bb[tid + 512];
}

// ---------------------------------------------------------------- prefix rows
__global__ __launch_bounds__(256) void prefix_k(const float* __restrict__ p, float* __restrict__ t)
{
    int idx = blockIdx.x * 256 + threadIdx.x;
    if (idx < BB * 7680) {
        int b = idx / 7680;
        int r = idx - b * 7680;
        t[(size_t)b * (NSEQ * DIM) + 7680 + r] = p[r];
    }
}

// ---------------------------------------------------------------- local attention
__global__ __launch_bounds__(256) void lattn_k(const float* __restrict__ q, const float* __restrict__ kv,
    float* __restrict__ ao)
{
    int b = blockIdx.x, h = blockIdx.y;
    __shared__ float sims[NSEQ][NSEQ];
    __shared__ float probs[NSEQ][NSEQ];
    const float* qb = q + (size_t)b * NSEQ * DIM + h * DH;
    const float* kb = kv + (size_t)b * NSEQ * 192;
    int tid = threadIdx.x;
    for (int p = tid; p < NSEQ * NSEQ; p += 256) {
        int i = p / NSEQ, j = p - i * NSEQ;
        float s;
        if (j > i) s = -1.0e9f;
        else {
            s = 0.f;
            for (int d = 0; d < DH; d++) s = fmaf(qb[(size_t)i * DIM + d], kb[j * 192 + d], s);
        }
        sims[i][j] = s;
    }
    __syncthreads();
    if (tid < NSEQ) {
        int i = tid;
        float m = -1e30f;
        for (int j = 0; j < NSEQ; j++) m = fmaxf(m, sims[i][j]);
        float sum = 0.f;
        for (int j = 0; j < NSEQ; j++) { float e = expf(sims[i][j] - m); probs[i][j] = e; sum += e; }
        float inv = 1.f / sum;
        for (int j = 0; j < NSEQ; j++) probs[i][j] *= inv;
    }
    __syncthreads();
    for (int p = tid; p < NSEQ * DH; p += 256) {
        int i = p / DH, d = p - i * DH;
        float o = 0.f;
        for (int j = 0; j <= i; j++) o = fmaf(probs[i][j], kb[j * 192 + 96 + d], o);
        ao[((size_t)b * NSEQ + i) * DIM + h * DH + d] = o;
    }
}

// ---------------------------------------------------------------- top-k helpers
__device__ __forceinline__ bool tk_better(float va, int ia, float vb, int ib) {
    return (va > vb) || (va == vb && ia < ib);
}

__device__ __forceinline__ void lds_fence() {
    asm volatile("s_waitcnt lgkmcnt(0)" ::: "memory");
    __builtin_amdgcn_sched_barrier(0);
}

// Exact top-32 of buf[0..cnt) by (value desc, idx asc). Bitonic-128 in regs.
__device__ void topk32(float* bv, int* bi, int cnt, int lane,
                       float& ov, int& oi, float& thr_out) {
    lds_fence();
    float v0 = (lane < cnt)      ? bv[lane]      : -3.0e38f;
    int   i0 = (lane < cnt)      ? bi[lane]      : 0x7fffffff;
    float v1 = (lane + 64 < cnt) ? bv[lane + 64] : -3.0e38f;
    int   i1 = (lane + 64 < cnt) ? bi[lane + 64] : 0x7fffffff;
    lds_fence();
#pragma unroll
    for (int k = 2; k <= 128; k <<= 1) {
#pragma unroll
        for (int j = 64; j >= 1; j >>= 1) {
            if (j >= k) continue;
            if (j == 64) {
                bool asc = ((lane & k) == 0);
                bool b01 = tk_better(v0, i0, v1, i1);
                if (b01 != asc) { float tv = v0; int ti = i0; v0 = v1; i0 = i1; v1 = tv; i1 = ti; }
            } else {
                {
                    float pv = __shfl_xor(v0, j); int pi = __shfl_xor(i0, j);
                    bool asc = ((lane & k) == 0);
                    bool first = ((lane & j) == 0);
                    bool mb = tk_better(v0, i0, pv, pi);
                    bool keep = first ? (mb == asc) : (mb != asc);
                    if (!keep) { v0 = pv; i0 = pi; }
                }
                {
                    float pv = __shfl_xor(v1, j); int pi = __shfl_xor(i1, j);
                    bool asc = (((lane + 64) & k) == 0);
                    bool first = ((lane & j) == 0);
                    bool mb = tk_better(v1, i1, pv, pi);
                    bool keep = first ? (mb == asc) : (mb != asc);
                    if (!keep) { v1 = pv; i1 = pi; }
                }
            }
        }
    }
    if (lane < 32) { bv[lane] = v0; bi[lane] = i0; }
    lds_fence();
    ov = v0; oi = i0;
    thr_out = __shfl(v0, 31);
}

// ---------------------------------------------------------------- mem top-k
// Block (c,h,b), 256 thr = 4 waves; wave w owns rows 5w..5w+4. Q in regs.
__global__ __launch_bounds__(256) void memtopk_k(const float* __restrict__ q, const float* __restrict__ memk,
    float* __restrict__ tkv, int* __restrict__ tki)
{
    __shared__ float bufv[NSEQ][CAP];
    __shared__ int   bufi[NSEQ][CAP];
    int c = blockIdx.x, h = blockIdx.y, b = blockIdx.z;
    int tid = threadIdx.x;
    int lane = tid & 63;
    int w = tid >> 6;
    int r0 = w * 5;
    int qt = lane & 3;
    int kk = lane >> 2;

    float4 qreg[5][6];
#pragma unroll
    for (int rr = 0; rr < 5; rr++) {
        const float4* qrow = (const float4*)(q + ((size_t)(b * NSEQ + r0 + rr)) * DIM + h * DH + qt * 24);
#pragma unroll
        for (int i = 0; i < 6; i++) qreg[rr][i] = qrow[i];
    }

    float thrR[5]; int cntR[5];
#pragma unroll
    for (int rr = 0; rr < 5; rr++) { thrR[rr] = -3.0e38f; cntR[rr] = 0; }

    const float* kb = memk + (size_t)b * KMEM * DH;
    int k0 = c * CHUNK;

    for (int p = 0; p < CHUNK / 16; p++) {
        int key = k0 + p * 16 + kk;
        const float4* krow = (const float4*)(kb + (size_t)key * DH + qt * 24);
        float a[5];
#pragma unroll
        for (int rr = 0; rr < 5; rr++) a[rr] = 0.f;
#pragma unroll
        for (int i = 0; i < 6; i++) {
            float4 kv = krow[i];
#pragma unroll
            for (int rr = 0; rr < 5; rr++) {
                float4 qv = qreg[rr][i];
                a[rr] = fmaf(qv.x, kv.x, a[rr]);
                a[rr] = fmaf(qv.y, kv.y, a[rr]);
                a[rr] = fmaf(qv.z, kv.z, a[rr]);
                a[rr] = fmaf(qv.w, kv.w, a[rr]);
            }
        }
#pragma unroll
        for (int rr = 0; rr < 5; rr++) {
            a[rr] += __shfl_xor(a[rr], 1);
            a[rr] += __shfl_xor(a[rr], 2);
        }
#pragma unroll
        for (int rr = 0; rr < 5; rr++) {
            bool cand = (qt == 0) && (a[rr] >= thrR[rr]);
            unsigned long long mask = __ballot(cand);
            int n = __popcll(mask);
            if (n) {
                int r = r0 + rr;
                if (cntR[rr] + n > CAP) {
                    float dv; int di;
                    topk32(&bufv[r][0], &bufi[r][0], cntR[rr], lane, dv, di, thrR[rr]);
                    cntR[rr] = 32;
                }
                int pos = cntR[rr] + __popcll(mask & ((1ull << lane) - 1ull));
                if (cand) { bufv[r][pos] = a[rr]; bufi[r][pos] = key; }
                cntR[rr] += n;
            }
        }
    }
#pragma unroll
    for (int rr = 0; rr < 5; rr++) {
        int r = r0 + rr;
        float ov; int oi; float dthr;
        topk32(&bufv[r][0], &bufi[r][0], cntR[rr], lane, ov, oi, dthr);
        if (lane < 32) {
            size_t base = ((((size_t)b * HEADS + h) * NSEQ + r) * NCHUNK + c) * 32;
            tkv[base + lane] = ov;
            tki[base + lane] = oi;
        }
    }
}

// ---------------------------------------------------------------- mem attention merge (per (i,h,b))
// Merges NCHUNK*32 = 256 candidates -> exact top-32 -> softmax with local -> output.
__global__ __launch_bounds__(64) void memattn_k(const float* __restrict__ q, const float* __restrict__ kv,
    const float* __restrict__ memv, const float* __restrict__ tkv, const int* __restrict__ tki,
    float* __restrict__ ao)
{
    int i = blockIdx.x, h = blockIdx.y, b = blockIdx.z;
    __shared__ float cv[NCHUNK * 32];
    __shared__ int   ci[NCHUNK * 32];
    __shared__ float selv[32];
    __shared__ int   seli[32];
    __shared__ float ls[NSEQ];
    __shared__ float probs[52];
    int tid = threadIdx.x;
    size_t base = (((size_t)b * HEADS + h) * NSEQ + i) * (NCHUNK * 32);
#pragma unroll
    for (int s = 0; s < NCHUNK * 32 / 64; s++) {
        cv[tid + 64 * s] = tkv[base + tid + 64 * s];
        ci[tid + 64 * s] = tki[base + tid + 64 * s];
    }
    const float* qr = q + ((size_t)b * NSEQ + i) * DIM + h * DH;
    const float* kvb = kv + (size_t)b * NSEQ * 192;
    if (tid <= i) {
        float s = 0.f;
        for (int d = 0; d < DH; d++) s = fmaf(qr[d], kvb[tid * 192 + d], s);
        ls[tid] = s;
    }
    __syncthreads();
    for (int r = 0; r < 32; r++) {
        float bv = -3.0e38f; int bidx = 0x7fffffff; int bs = 0;
#pragma unroll
        for (int s = 0; s < NCHUNK * 32 / 64; s++) {
            float v = cv[tid + 64 * s]; int ix = ci[tid + 64 * s];
            if (tk_better(v, ix, bv, bidx)) { bv = v; bidx = ix; bs = tid + 64 * s; }
        }
        for (int off = 32; off; off >>= 1) {
            float ovv = __shfl_down(bv, off);
            int oii = __shfl_down(bidx, off);
            int oss = __shfl_down(bs, off);
            if (tk_better(ovv, oii, bv, bidx)) { bv = ovv; bidx = oii; bs = oss; }
        }
        if (tid == 0) { selv[r] = bv; seli[r] = bidx; cv[bs] = -3.0e38f; }
        __syncthreads();
    }
    if (tid == 0) {
        float m = -1e30f;
        for (int r = 0; r < 32; r++) m = fmaxf(m, selv[r]);
        for (int j = 0; j <= i; j++) m = fmaxf(m, ls[j]);
        float sum = 0.f;
        for (int r = 0; r < 32; r++) { float e = expf(selv[r] - m); probs[r] = e; sum += e; }
        for (int j = 0; j <= i; j++) { float e = expf(ls[j] - m); probs[32 + j] = e; sum += e; }
        float inv = 1.f / sum;
        for (int r = 0; r < 32 + i + 1; r++) probs[r] *= inv;
    }
    __syncthreads();
    const float* mvb = memv + (size_t)b * KMEM * DH;
    for (int d = tid; d < DH; d += 64) {
        float o = 0.f;
        for (int r = 0; r < 32; r++) o = fmaf(probs[r], mvb[(size_t)seli[r] * DH + d], o);
        for (int j = 0; j <= i; j++) o = fmaf(probs[32 + j], kvb[j * 192 + 96 + d], o);
        ao[((size_t)b * NSEQ + i) * DIM + h * DH + d] = o;
    }
}

// ---------------------------------------------------------------- host
extern "C" void kernel_launch(void* const* d_in, const int* in_sizes, int n_in,
                              void* d_out, int out_size, void* d_ws, size_t ws_size,
                              hipStream_t stream) {
    const float* x            = (const float*)d_in[0];
    const float* linear_w     = (const float*)d_in[1];
    const float* linear_b     = (const float*)d_in[2];
    const float* prefix_const = (const float*)d_in[3];
    const float* ln1_g        = (const float*)d_in[4];
    const float* ln1_b        = (const float*)d_in[5];
    const float* wq           = (const float*)d_in[6];
    const float* wkv          = (const float*)d_in[7];
    const float* wo           = (const float*)d_in[8];
    const float* ln2_g        = (const float*)d_in[9];
    const float* ln2_b        = (const float*)d_in[10];
    const float* w1           = (const float*)d_in[11];
    const float* b1           = (const float*)d_in[12];
    const float* w2           = (const float*)d_in[13];
    const float* b2           = (const float*)d_in[14];
    const float* lnf_g        = (const float*)d_in[15];
    const float* lnf_b        = (const float*)d_in[16];
    const float* mem_k        = (const float*)d_in[17];
    const float* mem_v        = (const float*)d_in[18];

    float* ws = (float*)d_ws;
    float* t   = ws;                   // 320*768
    float* y   = ws + 245760;
    float* qb  = ws + 491520;
    float* kvb = ws + 737280;          // 320*192
    float* ao  = ws + 798720;
    float* h1  = ws + 1044480;         // 320*3072 -> ends 2027520
    float* tkv = ws + 2027520;         // 16*8*20*8*32 = 655360
    int*   tki = (int*)(ws + 2682880); // 655360
    float* out = (float*)d_out;

    const float qscale = 0.10206207261596577f; // 96^-0.5

    gemm_mfma<<<dim3(60, 1), 256, 0, stream>>>(x, linear_w, linear_b, nullptr, t,
                                               16, 7680, 640, 640, 15360, 1.f, 0);
    prefix_k<<<dim3(480), 256, 0, stream>>>(prefix_const, t);

    for (int l = 0; l < 8; l++) {
        ln_k<<<320, 256, 0, stream>>>(t, ln1_g + (size_t)l * DIM, ln1_b + (size_t)l * DIM, y);
        gemm_mfma<<<dim3(6, 20), 256, 0, stream>>>(y, wq + (size_t)l * DIM * DIM, nullptr, nullptr, qb,
                                                   320, 768, 768, 768, 768, qscale, 0);
        gemm_mfma<<<dim3(2, 20), 256, 0, stream>>>(y, wkv + (size_t)l * DIM * 192, nullptr, nullptr, kvb,
                                                   320, 192, 768, 768, 192, 1.f, 0);
        if (l == 4 || l == 5) {
            memtopk_k<<<dim3(NCHUNK, HEADS, BB), 256, 0, stream>>>(qb, mem_k, tkv, tki);
            memattn_k<<<dim3(NSEQ, HEADS, BB), 64, 0, stream>>>(qb, kvb, mem_v, tkv, tki, ao);
        } else {
            lattn_k<<<dim3(BB, HEADS), 256, 0, stream>>>(qb, kvb, ao);
        }
        gemm_mfma<<<dim3(6, 20), 256, 0, stream>>>(ao, wo + (size_t)l * DIM * DIM, nullptr, t, t,
                                                   320, 768, 768, 768, 768, 1.f, 0);
        ln_k<<<320, 256, 0, stream>>>(t, ln2_g + (size_t)l * DIM, ln2_b + (size_t)l * DIM, y);
        gemm_mfma<<<dim3(24, 20), 256, 0, stream>>>(y, w1 + (size_t)l * DIM * FF, b1 + (size_t)l * FF, nullptr, h1,
                                                    320, 3072, 768, 768, 3072, 1.f, 1);
        gemm_mfma<<<dim3(6, 20), 256, 0, stream>>>(h1, w2 + (size_t)l * FF * DIM, b2 + (size_t)l * DIM, t, t,
                                                   320, 768, 3072, 3072, 768, 1.f, 0);
    }
    lnf_k<<<160, 256, 0, stream>>>(t, lnf_g, lnf_b, out);
}